// Round 12
// baseline (266.147 us; speedup 1.0000x reference)
//
#include <hip/hip_runtime.h>
#include <cstdint>
#include <cstddef>

typedef unsigned short ushort_t;
typedef unsigned int uint;

typedef __attribute__((ext_vector_type(8))) short short8;   // 8 x bf16 (4 VGPRs)
typedef __attribute__((ext_vector_type(4))) float floatx4;  // 4 x f32

#define CDIM 768

// ---------- bf16 helpers (raw ushort representation) ----------
__device__ __forceinline__ float bfu(ushort_t u) {
    return __uint_as_float(((uint)u) << 16);
}
__device__ __forceinline__ void bf2(uint u, float& lo, float& hi) {
    lo = __uint_as_float(u << 16);
    hi = __uint_as_float(u & 0xffff0000u);
}
__device__ __forceinline__ ushort_t f2bfu(float f) {
    uint u = __float_as_uint(f);
    u += 0x7fffu + ((u >> 16) & 1u);   // round-to-nearest-even
    return (ushort_t)(u >> 16);
}
__device__ __forceinline__ uint pack2(float a, float b) {     // RNE pack
    return (uint)f2bfu(a) | ((uint)f2bfu(b) << 16);
}
// packed RNE f32x2 -> bf16x2 (low word = first operand), 1 VALU inst
__device__ __forceinline__ uint cvt2(float lo, float hi) {
    uint r;
    asm("v_cvt_pk_bf16_f32 %0, %1, %2" : "=v"(r) : "v"(lo), "v"(hi));
    return r;
}
__device__ __forceinline__ short8 mk8(uint a, uint b, uint c, uint d) {
    union { uint4 u; short8 s; } x;
    x.u = (uint4){a, b, c, d};
    return x.s;
}
__device__ __forceinline__ void gload_lds16(const void* g, void* l) {
    __builtin_amdgcn_global_load_lds(
        (__attribute__((address_space(1))) void*)(uintptr_t)g,
        (__attribute__((address_space(3))) void*)l, 16, 0, 0);
}

// ---------- Kernel 0: cvt_all = cvt_a (24576 blocks) + cvt_w (864) +
// init_agent (96) + bias_ab (1). prep rides along the GPU-filling cvt grid. --
__global__ __launch_bounds__(256) void cvt_all(
    const float* __restrict__ s1, const float* __restrict__ s2,
    const float* __restrict__ Wq, const float* __restrict__ Wk,
    const float* __restrict__ Wv, const float* __restrict__ bq,
    const float* __restrict__ na, const float* __restrict__ ha,
    const float* __restrict__ wa,
    ushort_t* __restrict__ abuf, ushort_t* __restrict__ wb,
    float* __restrict__ agent, float* __restrict__ ab)
{
    const int bid = blockIdx.x;
    if (bid < 24576) {
        // s1/s2 (fp32) -> bf16 activations
        const int m = (bid >= 12288);
        const int bx = bid - m * 12288;
        const float* src = (m == 0) ? s1 : s2;
        ushort_t* dst = abuf + (size_t)m * 25165824;
        const size_t i = ((size_t)bx * 256 + threadIdx.x) * 8;
        const float4 f0 = *(const float4*)(src + i);
        const float4 f1 = *(const float4*)(src + i + 4);
        uint4 u;
        u.x = pack2(f0.x, f0.y);
        u.y = pack2(f0.z, f0.w);
        u.z = pack2(f1.x, f1.y);
        u.w = pack2(f1.z, f1.w);
        *(uint4*)(dst + i) = u;
    } else if (bid < 25440) {
        // Wq/Wk/Wv (fp32) -> bf16 RNE
        const int wid = bid - 24576;
        const int m = wid / 288;
        const float* src = (m == 0) ? Wq : (m == 1 ? Wk : Wv);
        ushort_t* dst = wb + (size_t)m * 589824;
        const int i = ((wid % 288) * 256 + threadIdx.x) * 8;
        const float4 f0 = *(const float4*)(src + i);
        const float4 f1 = *(const float4*)(src + i + 4);
        uint4 u;
        u.x = pack2(f0.x, f0.y);
        u.y = pack2(f0.z, f0.w);
        u.z = pack2(f1.x, f1.y);
        u.w = pack2(f1.z, f1.w);
        *(uint4*)(dst + i) = u;
    } else if (bid < 25536) {
        // init agent accumulator with the q-bias
        const int bh = bid - 25440;
        const int h = bh % 12;
        for (int i = threadIdx.x; i < 1024; i += 256)
            agent[(size_t)bh * 1024 + i] = bq[h * 64 + (i & 63)];
    } else {
        // stage-2 agent bias ab[h][a]
        const int t = threadIdx.x;
        if (t >= 192) return;
        const int h = t >> 4, a = t & 15;
        const float cw[7] = {2.25f, 2.34375f, 2.28125f, 2.25f, 2.28125f, 2.34375f, 2.25f};
        float acc = 0.f;
        const float* nb = na + (h * 16 + a) * 49;
        for (int i = 0; i < 7; ++i)
            for (int j = 0; j < 7; ++j)
                acc += cw[i] * cw[j] * nb[i * 7 + j];
        acc *= (1.0f / 256.0f);
        float s = 0.f;
        for (int p = 0; p < 16; ++p)
            s += ha[(h * 16 + p) * 16 + a] + wa[(h * 16 + p) * 16 + a];
        ab[t] = acc + s * (1.0f / 16.0f);
    }
}

// ---------- Kernel 1: fused QKV GEMM — 256x256 tile, 8-wave, 8-phase schedule
// (m201 template: counted vmcnt, per-phase {ds-read quad || stage half-tile ->
// s_barrier -> lgkmcnt(0) -> setprio(1) -> 16 MFMA -> setprio(0) -> barrier}).
// LDS layout + chunk-XOR swizzle + gload_lds staging geometry carried over
// from the round-0..11 verified kernel (0 main-loop bank conflicts).
// Race-freedom: staging map {ph1,2: A(2i+1); ph3,4: B(2i+2); ph5,6: A(2i+2);
// ph7,8: B(2i+3)} — every region's last ds_read is consumed before the barrier
// preceding its overwriting gload issue. Boundary vmcnt(4) (= 2 half-tiles
// legitimately in flight); vmcnt(0) only at the i=5 tail.
__global__ __launch_bounds__(512, 1) void gemm_qkv(
    const ushort_t* __restrict__ ab, const ushort_t* __restrict__ wb,
    const float* __restrict__ bq, const float* __restrict__ bk, const float* __restrict__ bv,
    ushort_t* __restrict__ qo, ushort_t* __restrict__ ko, ushort_t* __restrict__ vo,
    float* __restrict__ agent)
{
    const int z = blockIdx.z;
    const ushort_t* A     = ab + (size_t)(z != 0) * 25165824;
    const ushort_t* W     = wb + (size_t)z * 589824;
    const float* bias     = (z == 0) ? bq : (z == 1 ? bk : bv);
    ushort_t* out         = (z == 0) ? qo : (z == 1 ? ko : vo);

    __shared__ ushort_t lds[65536];   // 128 KiB: A buf0/buf1 @0/16384, W @32768/49152
    // epilogue reuses [0 .. 33792) as [128][264]

    const int tid  = threadIdx.x;
    const int wave = tid >> 6;
    const int lane = tid & 63;
    const int wm = wave >> 2, wn = wave & 3;   // 2 x 4 wave grid

    // XCD swizzle: 384 blocks/plane, 8 XCDs, 48/chunk (bijective: 384%8==0).
    // id2/3 = row-panel, id2%3 = col-block -> 3 consecutive blocks on one XCD
    // share an A panel (1 HBM read + 2 L2 hits).
    const int id  = blockIdx.x;
    const int id2 = (id & 7) * 48 + (id >> 3);
    const int row0 = (id2 / 3) * 256;   // token rows (b*4096+m)
    const int col0 = (id2 % 3) * 256;   // output channels

    // staging geometry (verified): lane j covers row_off j>>3, src chunk (j&7)^(j>>3)
    const int sro = lane >> 3;
    const int sch = ((lane & 7) ^ sro) * 8;
    const ushort_t* gaBase = A + (size_t)(row0 + wave * 8 + sro) * CDIM + sch;
    const ushort_t* gwBase = W + (size_t)(col0 + wave * 8 + sro) * CDIM + sch;

    // stage one 128-row half-tile (2 x gload_lds16/thread) of K-tile t
    auto stageA = [&](int half, int t) {
        const ushort_t* g = gaBase + (size_t)(half * 128) * CDIM + t * 64;
        ushort_t* l = &lds[(t & 1) * 16384 + (half * 128 + wave * 8) * 64];
        gload_lds16(g, l);
        gload_lds16(g + (size_t)64 * CDIM, l + 64 * 64);
    };
    auto stageB = [&](int half, int t) {
        const ushort_t* g = gwBase + (size_t)(half * 128) * CDIM + t * 64;
        ushort_t* l = &lds[32768 + (t & 1) * 16384 + (half * 128 + wave * 8) * 64];
        gload_lds16(g, l);
        gload_lds16(g + (size_t)64 * CDIM, l + 64 * 64);
    };

    floatx4 acc[8][4];
    #pragma unroll
    for (int i = 0; i < 8; ++i)
        #pragma unroll
        for (int j = 0; j < 4; ++j)
            acc[i][j] = (floatx4){0.f, 0.f, 0.f, 0.f};

    const int q4 = lane >> 4, r16 = lane & 15;

    short8 af[4][2], bf0[2][2], bf1[2][2];

    // read A sub-quadrant MH (4 mt x 2 ks) of buffer BUF
    #define RD_A(MH, BUF)                                                        \
        _Pragma("unroll")                                                        \
        for (int mtl = 0; mtl < 4; ++mtl) {                                      \
            const int row = wm * 128 + (MH) * 64 + mtl * 16 + r16;               \
            _Pragma("unroll")                                                    \
            for (int ks = 0; ks < 2; ++ks) {                                     \
                const int ch = (ks * 4 + q4) ^ (row & 7);                        \
                af[mtl][ks] = *(const short8*)&lds[(BUF) * 16384 + row * 64 + ch * 8]; \
            }                                                                    \
        }
    #define RD_B(DST, NH, BUF)                                                   \
        _Pragma("unroll")                                                        \
        for (int ntl = 0; ntl < 2; ++ntl) {                                      \
            const int row = wn * 64 + (NH) * 32 + ntl * 16 + r16;                \
            _Pragma("unroll")                                                    \
            for (int ks = 0; ks < 2; ++ks) {                                     \
                const int ch = (ks * 4 + q4) ^ (row & 7);                        \
                DST[ntl][ks] = *(const short8*)&lds[32768 + (BUF) * 16384 + row * 64 + ch * 8]; \
            }                                                                    \
        }
    #define MFMA_Q(MH, NH, BF)                                                   \
        _Pragma("unroll")                                                        \
        for (int mtl = 0; mtl < 4; ++mtl)                                        \
            _Pragma("unroll")                                                    \
            for (int ntl = 0; ntl < 2; ++ntl)                                    \
                _Pragma("unroll")                                                \
                for (int ks = 0; ks < 2; ++ks)                                   \
                    acc[(MH)*4+mtl][(NH)*2+ntl] =                                \
                        __builtin_amdgcn_mfma_f32_16x16x32_bf16(                 \
                            af[mtl][ks], BF[ntl][ks], acc[(MH)*4+mtl][(NH)*2+ntl], 0, 0, 0);
    #define SYNC_MFMA(MH, NH, BF)                                                \
        __builtin_amdgcn_s_barrier();                                            \
        asm volatile("s_waitcnt lgkmcnt(0)" ::: "memory");                       \
        __builtin_amdgcn_sched_barrier(0);                                       \
        __builtin_amdgcn_s_setprio(1);                                           \
        MFMA_Q(MH, NH, BF);                                                      \
        __builtin_amdgcn_s_setprio(0);

    // prologue: "virtual iteration -1" staging: tile0 {B0,B1,A0,A1} + tile1 {B0,B1}
    stageB(0, 0); stageB(1, 0); stageA(0, 0); stageA(1, 0);
    stageB(0, 1); stageB(1, 1);
    asm volatile("s_waitcnt vmcnt(4)" ::: "memory");   // tile0 resident, tile1-B in flight
    __builtin_amdgcn_s_barrier();

    #pragma unroll 1
    for (int it = 0; it < 6; ++it) {
        const bool full = (it < 5);
        // ---- tile 2it (buf0): phases 1-4 ----
        RD_B(bf0, 0, 0); RD_A(0, 0);
        stageA(0, 2 * it + 1);
        SYNC_MFMA(0, 0, bf0);
        __builtin_amdgcn_s_barrier();

        RD_B(bf1, 1, 0);
        stageA(1, 2 * it + 1);
        SYNC_MFMA(0, 1, bf1);
        __builtin_amdgcn_s_barrier();

        RD_A(1, 0);
        if (full) stageB(0, 2 * it + 2);
        SYNC_MFMA(1, 1, bf1);
        __builtin_amdgcn_s_barrier();

        if (full) stageB(1, 2 * it + 2);
        SYNC_MFMA(1, 0, bf0);
        if (full) { asm volatile("s_waitcnt vmcnt(4)" ::: "memory"); }
        else      { asm volatile("s_waitcnt vmcnt(0)" ::: "memory"); }
        __builtin_amdgcn_s_barrier();

        // ---- tile 2it+1 (buf1): phases 5-8 ----
        RD_B(bf0, 0, 1); RD_A(0, 1);
        if (full) stageA(0, 2 * it + 2);
        SYNC_MFMA(0, 0, bf0);
        __builtin_amdgcn_s_barrier();

        RD_B(bf1, 1, 1);
        if (full) stageA(1, 2 * it + 2);
        SYNC_MFMA(0, 1, bf1);
        __builtin_amdgcn_s_barrier();

        RD_A(1, 1);
        if (full) stageB(0, 2 * it + 3);
        SYNC_MFMA(1, 1, bf1);
        __builtin_amdgcn_s_barrier();

        if (full) stageB(1, 2 * it + 3);
        SYNC_MFMA(1, 0, bf0);
        if (full) { asm volatile("s_waitcnt vmcnt(4)" ::: "memory"); }
        __builtin_amdgcn_s_barrier();
    }
    #undef RD_A
    #undef RD_B
    #undef MFMA_Q
    #undef SYNC_MFMA

    // ---- epilogue ----
    const int b = row0 >> 12;
    const int m_base = row0 & 4095;

    // fused adaptive-avg-pool (z==0): block covers exactly one agent chunk
    // (256 rows); each wave contributes its 128-row partial (2 atomics/col).
    if (z == 0) {
        #pragma unroll
        for (int nt = 0; nt < 4; ++nt) {
            const int coll = wn * 64 + nt * 16 + r16;
            float psum = 0.f;
            #pragma unroll
            for (int mt = 0; mt < 8; ++mt)
                #pragma unroll
                for (int r = 0; r < 4; ++r)
                    psum += acc[mt][nt][r];
            psum += __shfl_xor(psum, 16);
            psum += __shfl_xor(psum, 32);
            if (q4 == 0) {
                const int col = col0 + coll;
                const int h = col >> 6, d = col & 63;
                atomicAdd(&agent[(size_t)(b * 12 + h) * 1024 + (m_base >> 8) * 64 + d],
                          psum * (1.0f / 256.0f));
            }
        }
    }

    // LDS-staged coalesced store (verified round 8 pattern), 2 x 128-row passes.
    #pragma unroll 1
    for (int hc = 0; hc < 2; ++hc) {
        __builtin_amdgcn_s_barrier();
        if (wm == hc) {
            #pragma unroll
            for (int nt = 0; nt < 4; ++nt) {
                const int coll = wn * 64 + nt * 16 + r16;
                const float bb = bias[col0 + coll];
                #pragma unroll
                for (int mh = 0; mh < 2; ++mh)
                    #pragma unroll
                    for (int mtl = 0; mtl < 4; ++mtl) {
                        const int rowl = mh * 64 + mtl * 16 + q4 * 4;
                        #pragma unroll
                        for (int r = 0; r < 4; ++r)
                            lds[(rowl + r) * 264 + coll] =
                                f2bfu(acc[mh * 4 + mtl][nt][r] + bb);
                    }
            }
        }
        __builtin_amdgcn_s_barrier();
        // 128 rows x 4 heads x 128 B; 8 x uint4 tasks per thread
        #pragma unroll
        for (int itr = 0; itr < 8; ++itr) {
            const int task  = itr * 512 + tid;
            const int chunk = task & 7;
            const int rh    = task >> 3;          // 0..511
            const int rowl  = rh >> 2, hl = rh & 3;
            const uint4 v = *(const uint4*)&lds[rowl * 264 + hl * 64 + chunk * 8];
            ushort_t* op = out + ((size_t)(b * 12 + (col0 >> 6) + hl) * 4096
                                  + m_base + hc * 128 + rowl) * 64 + chunk * 8;
            *(uint4*)op = v;
        }
    }
}

// ---------- Kernel 4: stage 1 (agent -> keys/values), MFMA scores, z-split x16 --
// Part A (MFMA, verified round 9): S^T[a][tok] = mfma(A=ah(value+residual),
// B=K-rows); exp + pack2 -> 8-B E2 store per lane.
// Part B (vectorized, verified round 10): lane covers a d-pair; 2-way m split;
// shfl_xor(32) combine; float2 stores. Sp transposed [bh][a][z2].
__global__ __launch_bounds__(512) void stage1(
    const ushort_t* __restrict__ k_hm, const ushort_t* __restrict__ v_hm,
    const float* __restrict__ agent, float* __restrict__ Sp, float* __restrict__ avp)
{
    const int bh = blockIdx.x, z = blockIdx.y;   // z in [0,16)
    const int tid = threadIdx.x;
    const int lane = tid & 63;
    const int w = tid >> 6;              // wave 0..7
    const int g = lane >> 4;             // quad group 0..3
    const int t = lane & 15;
    __shared__ ushort_t E2[256 * 20];    // [m_local][a] bf16, rows padded to 40 B

    // ah A-fragments (value + residual), scale 0.125 — identical to stage2's
    short8 ahA[2], ahE[2];
    #pragma unroll
    for (int k0 = 0; k0 < 2; ++k0) {
        const float* p = agent + (size_t)bh * 1024 + t * 64 + k0 * 32 + g * 8;
        const float4 f0 = *(const float4*)p;
        const float4 f1 = *(const float4*)(p + 4);
        const float v[8] = {f0.x, f0.y, f0.z, f0.w, f1.x, f1.y, f1.z, f1.w};
        uint u[4], e[4];
        #pragma unroll
        for (int j = 0; j < 4; ++j) {
            const float a0 = v[2*j] * 0.125f, a1 = v[2*j+1] * 0.125f;
            u[j] = cvt2(a0, a1);
            float b0, b1; bf2(u[j], b0, b1);
            e[j] = cvt2(a0 - b0, a1 - b1);
        }
        ahA[k0] = mk8(u[0], u[1], u[2], u[3]);
        ahE[k0] = mk8(e[0], e[1], e[2], e[3]);
    }

    const int m0 = z * 256;
    const ushort_t* kb = k_hm + ((size_t)bh * 4096 + m0) * 64;

    #pragma unroll
    for (int ti = 0; ti < 2; ++ti) {
        const int row = w * 32 + ti * 16 + t;
        const ushort_t* kp = kb + (size_t)row * 64 + g * 8;
        const short8 kB0 = *(const short8*)(kp);
        const short8 kB1 = *(const short8*)(kp + 32);
        floatx4 sc = {0.f, 0.f, 0.f, 0.f};
        sc = __builtin_amdgcn_mfma_f32_16x16x32_bf16(ahA[0], kB0, sc, 0, 0, 0);
        sc = __builtin_amdgcn_mfma_f32_16x16x32_bf16(ahA[1], kB1, sc, 0, 0, 0);
        sc = __builtin_amdgcn_mfma_f32_16x16x32_bf16(ahE[0], kB0, sc, 0, 0, 0);
        sc = __builtin_amdgcn_mfma_f32_16x16x32_bf16(ahE[1], kB1, sc, 0, 0, 0);
        const uint P0 = pack2(__expf(sc[0]), __expf(sc[1]));
        const uint P1 = pack2(__expf(sc[2]), __expf(sc[3]));
        *(uint2*)&E2[(size_t)row * 20 + g * 4] = make_uint2(P0, P1);
    }
    __syncthreads();

    // part B: quad gg of agents, half of m (128 rows), mseg splits it 2x64;
    // lane ls covers d-pair (d0, d0+1).
    const int gg = (tid >> 6) & 3;
    const int half = tid >> 8;           // 0/1
    const int ls = lane & 31;
    const int mseg = lane >> 5;          // 0/1
    const int d0 = ls * 2;
    const int mb = half * 128 + mseg * 64;
    const ushort_t* vb = v_hm + ((size_t)bh * 4096 + m0 + mb) * 64 + d0;
    float ac[4][2];
    float ss[4];
    #pragma unroll
    for (int a = 0; a < 4; ++a) { ac[a][0] = 0.f; ac[a][1] = 0.f; ss[a] = 0.f; }
    for (int ml = 0; ml < 64; ++ml) {
        const uint vv = *(const uint*)(vb + (size_t)ml * 64);
        float v0, v1;
        bf2(vv, v0, v1);
        const uint2 ee = *(const uint2*)&E2[(size_t)(mb + ml) * 20 + gg * 4];
        float e0, e1, e2, e3;
        bf2(ee.x, e0, e1);
        bf2(ee.y, e2, e3);
        ac[0][0] += e0 * v0; ac[0][1] += e0 * v1; ss[0] += e0;
        ac[1][0] += e1 * v0; ac[1][1] += e1 * v1; ss[1] += e1;
        ac[2][0] += e2 * v0; ac[2][1] += e2 * v1; ss[2] += e2;
        ac[3][0] += e3 * v0; ac[3][1] += e3 * v1; ss[3] += e3;
    }
    #pragma unroll
    for (int a = 0; a < 4; ++a) {
        ac[a][0] += __shfl_xor(ac[a][0], 32);
        ac[a][1] += __shfl_xor(ac[a][1], 32);
        ss[a]    += __shfl_xor(ss[a], 32);
    }
    const int z2 = z * 2 + half;         // 0..31
    if (mseg == 0) {
        float* avz = avp + (size_t)(z2 * 96 + bh) * 1024;
        #pragma unroll
        for (int a = 0; a < 4; ++a)
            *(float2*)&avz[(gg * 4 + a) * 64 + d0] = make_float2(ac[a][0], ac[a][1]);
        if (ls == 0) {
            #pragma unroll
            for (int a = 0; a < 4; ++a)
                Sp[((size_t)bh * 16 + gg * 4 + a) * 32 + z2] = ss[a];
        }
    }
}

// ---------- Kernel 4b: reduce partials -> normalized agent_v (once per bh) ----
__global__ __launch_bounds__(256) void redu(
    const float* __restrict__ avp, const float* __restrict__ Sp,
    float* __restrict__ avn_g)
{
    const int bh = blockIdx.x;
    const int tid = threadIdx.x;
    const int i4 = tid * 4;
    const int a = i4 >> 6;
    floatx4 num = {0.f, 0.f, 0.f, 0.f};
    #pragma unroll
    for (int zz = 0; zz < 32; ++zz)
        num += *(const floatx4*)&avp[(size_t)(zz * 96 + bh) * 1024 + i4];
    const float* sp = Sp + ((size_t)bh * 16 + a) * 32;
    floatx4 dv = {0.f, 0.f, 0.f, 0.f};
    #pragma unroll
    for (int j = 0; j < 8; ++j)
        dv += *(const floatx4*)(sp + j * 4);
    const float r = 1.0f / (dv[0] + dv[1] + dv[2] + dv[3]);
    *(floatx4*)&avn_g[(size_t)bh * 1024 + i4] = num * r;
}

// ---------- Kernel 5: stage 2 (queries -> agents) via MFMA ----------
// Swapped-operand scheme (verified round 5). avn pre-reduced by redu.
__global__ __launch_bounds__(256) void stage2(
    const ushort_t* __restrict__ q_hm, const float* __restrict__ avn_g,
    const float* __restrict__ agent, const float* __restrict__ ab,
    float* __restrict__ out)
{
    const int nb = blockIdx.x;           // 16
    const int bh = blockIdx.y;           // 96
    const int b = bh / 12, h = bh % 12;
    const int tid = threadIdx.x;
    const int g = (tid >> 4) & 3;        // lane>>4 (quad group)
    const int t = tid & 15;              // lane&15
    const int w = tid >> 6;              // wave
    __shared__ float avn[1024];          // normalized agent_v, [a][d] fp32

    {
        const int i4 = tid * 4;
        *(floatx4*)&avn[i4] = *(const floatx4*)&avn_g[(size_t)bh * 1024 + i4];
    }
    __syncthreads();

    // ah A-fragments (value + residual): lane holds ah[t][k0*32 + g*8 + j]*scale
    short8 ahA[2], ahE[2];
    #pragma unroll
    for (int k0 = 0; k0 < 2; ++k0) {
        const float* p = agent + (size_t)bh * 1024 + t * 64 + k0 * 32 + g * 8;
        const float4 f0 = *(const float4*)p;
        const float4 f1 = *(const float4*)(p + 4);
        const float v[8] = {f0.x, f0.y, f0.z, f0.w, f1.x, f1.y, f1.z, f1.w};
        uint u[4], e[4];
        #pragma unroll
        for (int j = 0; j < 4; ++j) {
            const float a0 = v[2*j] * 0.125f, a1 = v[2*j+1] * 0.125f;
            u[j] = cvt2(a0, a1);
            float b0, b1; bf2(u[j], b0, b1);
            e[j] = cvt2(a0 - b0, a1 - b1);
        }
        ahA[k0] = mk8(u[0], u[1], u[2], u[3]);
        ahE[k0] = mk8(e[0], e[1], e[2], e[3]);
    }

    // av^T A-fragments (value + residual): lane holds avn[8g+j][dt*16 + t]; g>=2 zero
    short8 avf[4], ave[4];
    #pragma unroll
    for (int dt = 0; dt < 4; ++dt) {
        uint u[4] = {0, 0, 0, 0}, e[4] = {0, 0, 0, 0};
        if (g < 2) {
            #pragma unroll
            for (int j = 0; j < 4; ++j) {
                const float a0 = avn[(8*g + 2*j)     * 64 + dt * 16 + t];
                const float a1 = avn[(8*g + 2*j + 1) * 64 + dt * 16 + t];
                u[j] = cvt2(a0, a1);
                float b0, b1; bf2(u[j], b0, b1);
                e[j] = cvt2(a0 - b0, a1 - b1);
            }
        }
        avf[dt] = mk8(u[0], u[1], u[2], u[3]);
        ave[dt] = mk8(e[0], e[1], e[2], e[3]);
    }

    float abv[4];
    #pragma unroll
    for (int r = 0; r < 4; ++r) abv[r] = ab[h * 16 + 4 * g + r];

    const int src0 = (t + 32 * g) & 63;
    const int src1 = (src0 + 16) & 63;
    const int n0 = nb * 256 + w * 64;
    const ushort_t* qb = q_hm + ((size_t)bh * 4096 + n0) * 64;
    float* ob = out + ((size_t)b * 4096 + n0) * CDIM + h * 64;

    #pragma unroll
    for (int ti = 0; ti < 4; ++ti) {
        // Q B-fragments: lane holds Q[ti*16+t][k0*32 + g*8 + j]
        const ushort_t* qp = qb + (size_t)(ti * 16 + t) * 64 + g * 8;
        const short8 qB0 = *(const short8*)(qp);
        const short8 qB1 = *(const short8*)(qp + 32);

        floatx4 sc = {0.f, 0.f, 0.f, 0.f};
        sc = __builtin_amdgcn_mfma_f32_16x16x32_bf16(ahA[0], qB0, sc, 0, 0, 0);
        sc = __builtin_amdgcn_mfma_f32_16x16x32_bf16(ahA[1], qB1, sc, 0, 0, 0);
        sc = __builtin_amdgcn_mfma_f32_16x16x32_bf16(ahE[0], qB0, sc, 0, 0, 0);
        sc = __builtin_amdgcn_mfma_f32_16x16x32_bf16(ahE[1], qB1, sc, 0, 0, 0);

        // softmax over agents (rows): in-lane + cross-group
        const float e0 = __expf(sc[0] + abv[0]);
        const float e1 = __expf(sc[1] + abv[1]);
        const float e2 = __expf(sc[2] + abv[2]);
        const float e3 = __expf(sc[3] + abv[3]);
        float s = e0 + e1 + e2 + e3;
        s += __shfl_xor(s, 16);
        s += __shfl_xor(s, 32);
        const float rs = 1.0f / s;
        const float p0 = e0 * rs, p1 = e1 * rs, p2 = e2 * rs, p3 = e3 * rs;

        // pack own P (agents 4g..4g+3, token t) + residual
        const uint P0 = cvt2(p0, p1), P1 = cvt2(p2, p3);
        float q0, q1, q2, q3;
        bf2(P0, q0, q1); bf2(P1, q2, q3);
        const uint E0 = cvt2(p0 - q0, p1 - q1), E1 = cvt2(p2 - q2, p3 - q3);

        // regroup into K=32-padded B-fragment: k=8g+j -> agents from groups 2g, 2g+1
        uint w0 = __shfl(P0, src0), w1 = __shfl(P1, src0);
        uint w2 = __shfl(P0, src1), w3 = __shfl(P1, src1);
        uint x0 = __shfl(E0, src0), x1 = __shfl(E1, src0);
        uint x2 = __shfl(E0, src1), x3 = __shfl(E1, src1);
        if (g >= 2) { w0 = w1 = w2 = w3 = 0; x0 = x1 = x2 = x3 = 0; }
        const short8 pf = mk8(w0, w1, w2, w3);
        const short8 pe = mk8(x0, x1, x2, x3);

        // PV: out^T[dt*16 + 4g + r][t], residual-corrected
        float* op = ob + (size_t)(ti * 16 + t) * CDIM + 4 * g;
        #pragma unroll
        for (int dt = 0; dt < 4; ++dt) {
            floatx4 od = {0.f, 0.f, 0.f, 0.f};
            od = __builtin_amdgcn_mfma_f32_16x16x32_bf16(avf[dt], pf, od, 0, 0, 0);
            od = __builtin_amdgcn_mfma_f32_16x16x32_bf16(avf[dt], pe, od, 0, 0, 0);
            od = __builtin_amdgcn_mfma_f32_16x16x32_bf16(ave[dt], pf, od, 0, 0, 0);
            *(floatx4*)(op + dt * 16) = od;
        }
    }
}

// ---------- launcher ----------
extern "C" void kernel_launch(void* const* d_in, const int* in_sizes, int n_in,
                              void* d_out, int out_size, void* d_ws, size_t ws_size,
                              hipStream_t stream) {
    (void)in_sizes; (void)n_in; (void)out_size; (void)ws_size;
    const float* s1 = (const float*)d_in[0];
    const float* s2 = (const float*)d_in[1];
    const float* Wq = (const float*)d_in[2];
    const float* bq = (const float*)d_in[3];
    const float* Wk = (const float*)d_in[4];
    const float* bk = (const float*)d_in[5];
    const float* Wv = (const float*)d_in[6];
    const float* bv = (const float*)d_in[7];
    const float* na = (const float*)d_in[9];
    const float* ha = (const float*)d_in[12];
    const float* wa = (const float*)d_in[13];
    float* out = (float*)d_out;

    char* ws = (char*)d_ws;
    ushort_t* q_hm = (ushort_t*)(ws);                 // 50,331,648 B  [96][4096][64]
    ushort_t* k_hm = (ushort_t*)(ws + 50331648);      // 50,331,648 B
    ushort_t* v_hm = (ushort_t*)(ws + 100663296);     // 50,331,648 B
    float* agent   = (float*)(ws + 150994944);        //    393,216 B  [96][16][64]
    float* Sp      = (float*)(ws + 151388160);        //    196,608 B  [96][16][32]  (transposed)
    float* ab      = (float*)(ws + 151584768);        //        768 B
    float* avn_g   = (float*)(ws + 151585536);        //    393,216 B  [96][16][64]
    ushort_t* wb   = (ushort_t*)(ws + 151978752);     //  3,538,944 B  [3][768][768]
    ushort_t* abuf = (ushort_t*)(ws + 155517696);     // 100,663,296 B [2][32768][768]  (live cvt..gemm)
    float* avp     = (float*)(ws + 155517696);        // 12,582,912 B  [32][96][16][64] (live stage1..redu, overlays dead abuf)

    cvt_all  <<<dim3(25537),     256, 0, stream>>>(s1, s2, Wq, Wk, Wv, bq,
                                                   na, ha, wa, abuf, wb, agent, ab);
    gemm_qkv <<<dim3(384, 1, 3), 512, 0, stream>>>(abuf, wb, bq, bk, bv,
                                                   q_hm, k_hm, v_hm, agent);
    stage1   <<<dim3(96, 16),    512, 0, stream>>>(k_hm, v_hm, agent, Sp, avp);
    redu     <<<dim3(96),        256, 0, stream>>>(avp, Sp, avn_g);
    stage2   <<<dim3(16, 96),    256, 0, stream>>>(q_hm, avn_g, agent, ab, out);
}

// Round 13
// 261.863 us; speedup vs baseline: 1.0164x; 1.0164x over previous
//
#include <hip/hip_runtime.h>
#include <cstdint>
#include <cstddef>

typedef unsigned short ushort_t;
typedef unsigned int uint;

typedef __attribute__((ext_vector_type(8))) short short8;   // 8 x bf16 (4 VGPRs)
typedef __attribute__((ext_vector_type(4))) float floatx4;  // 4 x f32

#define CDIM 768

// ---------- bf16 helpers (raw ushort representation) ----------
__device__ __forceinline__ float bfu(ushort_t u) {
    return __uint_as_float(((uint)u) << 16);
}
__device__ __forceinline__ void bf2(uint u, float& lo, float& hi) {
    lo = __uint_as_float(u << 16);
    hi = __uint_as_float(u & 0xffff0000u);
}
__device__ __forceinline__ ushort_t f2bfu(float f) {
    uint u = __float_as_uint(f);
    u += 0x7fffu + ((u >> 16) & 1u);   // round-to-nearest-even
    return (ushort_t)(u >> 16);
}
__device__ __forceinline__ uint pack2(float a, float b) {     // RNE pack
    return (uint)f2bfu(a) | ((uint)f2bfu(b) << 16);
}
// packed RNE f32x2 -> bf16x2 (low word = first operand), 1 VALU inst
__device__ __forceinline__ uint cvt2(float lo, float hi) {
    uint r;
    asm("v_cvt_pk_bf16_f32 %0, %1, %2" : "=v"(r) : "v"(lo), "v"(hi));
    return r;
}
__device__ __forceinline__ short8 mk8(uint a, uint b, uint c, uint d) {
    union { uint4 u; short8 s; } x;
    x.u = (uint4){a, b, c, d};
    return x.s;
}
__device__ __forceinline__ void gload_lds16(const void* g, void* l) {
    __builtin_amdgcn_global_load_lds(
        (__attribute__((address_space(1))) void*)(uintptr_t)g,
        (__attribute__((address_space(3))) void*)l, 16, 0, 0);
}

// ---------- Kernel 0: cvt_all = cvt_a (24576 blocks) + cvt_w (864) +
// init_agent (96) + bias_ab (1). prep rides along the GPU-filling cvt grid. --
__global__ __launch_bounds__(256) void cvt_all(
    const float* __restrict__ s1, const float* __restrict__ s2,
    const float* __restrict__ Wq, const float* __restrict__ Wk,
    const float* __restrict__ Wv, const float* __restrict__ bq,
    const float* __restrict__ na, const float* __restrict__ ha,
    const float* __restrict__ wa,
    ushort_t* __restrict__ abuf, ushort_t* __restrict__ wb,
    float* __restrict__ agent, float* __restrict__ ab)
{
    const int bid = blockIdx.x;
    if (bid < 24576) {
        // s1/s2 (fp32) -> bf16 activations
        const int m = (bid >= 12288);
        const int bx = bid - m * 12288;
        const float* src = (m == 0) ? s1 : s2;
        ushort_t* dst = abuf + (size_t)m * 25165824;
        const size_t i = ((size_t)bx * 256 + threadIdx.x) * 8;
        const float4 f0 = *(const float4*)(src + i);
        const float4 f1 = *(const float4*)(src + i + 4);
        uint4 u;
        u.x = pack2(f0.x, f0.y);
        u.y = pack2(f0.z, f0.w);
        u.z = pack2(f1.x, f1.y);
        u.w = pack2(f1.z, f1.w);
        *(uint4*)(dst + i) = u;
    } else if (bid < 25440) {
        // Wq/Wk/Wv (fp32) -> bf16 RNE
        const int wid = bid - 24576;
        const int m = wid / 288;
        const float* src = (m == 0) ? Wq : (m == 1 ? Wk : Wv);
        ushort_t* dst = wb + (size_t)m * 589824;
        const int i = ((wid % 288) * 256 + threadIdx.x) * 8;
        const float4 f0 = *(const float4*)(src + i);
        const float4 f1 = *(const float4*)(src + i + 4);
        uint4 u;
        u.x = pack2(f0.x, f0.y);
        u.y = pack2(f0.z, f0.w);
        u.z = pack2(f1.x, f1.y);
        u.w = pack2(f1.z, f1.w);
        *(uint4*)(dst + i) = u;
    } else if (bid < 25536) {
        // init agent accumulator with the q-bias
        const int bh = bid - 25440;
        const int h = bh % 12;
        for (int i = threadIdx.x; i < 1024; i += 256)
            agent[(size_t)bh * 1024 + i] = bq[h * 64 + (i & 63)];
    } else {
        // stage-2 agent bias ab[h][a]
        const int t = threadIdx.x;
        if (t >= 192) return;
        const int h = t >> 4, a = t & 15;
        const float cw[7] = {2.25f, 2.34375f, 2.28125f, 2.25f, 2.28125f, 2.34375f, 2.25f};
        float acc = 0.f;
        const float* nb = na + (h * 16 + a) * 49;
        for (int i = 0; i < 7; ++i)
            for (int j = 0; j < 7; ++j)
                acc += cw[i] * cw[j] * nb[i * 7 + j];
        acc *= (1.0f / 256.0f);
        float s = 0.f;
        for (int p = 0; p < 16; ++p)
            s += ha[(h * 16 + p) * 16 + a] + wa[(h * 16 + p) * 16 + a];
        ab[t] = acc + s * (1.0f / 16.0f);
    }
}

// ---------- Kernel 1: fused QKV GEMM (round-0 structure: all-bf16, pure
// global_load_lds staging) + XCD swizzle + fused agent pooling + LDS-staged
// coalesced epilogue (verified round 8: WRITE_SIZE at ideal 148,992 KB).
// [Round 12 measured: 8-phase 256^2 template is shape-mismatched here
//  (K=768 -> 12 tiles, pipeline never fills; 146 us vs this 143) — reverted.]
__global__ __launch_bounds__(256, 2) void gemm_qkv(
    const ushort_t* __restrict__ ab, const ushort_t* __restrict__ wb,
    const float* __restrict__ bq, const float* __restrict__ bk, const float* __restrict__ bv,
    ushort_t* __restrict__ qo, ushort_t* __restrict__ ko, ushort_t* __restrict__ vo,
    float* __restrict__ agent)
{
    const int z = blockIdx.z;
    const ushort_t* A     = ab + (size_t)(z != 0) * 25165824;
    const ushort_t* W     = wb + (size_t)z * 589824;
    const float* bias     = (z == 0) ? bq : (z == 1 ? bk : bv);
    ushort_t* out         = (z == 0) ? qo : (z == 1 ? ko : vo);

    __shared__ ushort_t lds[17408];     // 34,816 B: At=[0:8192], Wt=[8192:16384];
    ushort_t* At = lds;                 // epilogue reuses all as [128][136]
    ushort_t* Wt = lds + 8192;

    const int tid  = threadIdx.x;
    const int wave = tid >> 6;
    const int lane = tid & 63;
    const int wm = wave >> 1, wn = wave & 1;

    // XCD-aware swizzle: 1536 blocks/plane, 8 XCDs, 192 blocks/chunk (bijective).
    const int id   = blockIdx.x + (blockIdx.y << 8);   // gridDim.x = 256
    const int id2  = (id & 7) * 192 + (id >> 3);
    const int row0 = (id2 / 6) * 128;   // token rows (b*4096+m)
    const int col0 = (id2 % 6) * 128;   // output channels

    // staging: lane j covers row_off = j>>3, source chunk = (j&7) ^ (j>>3)
    const int sro = lane >> 3;
    const int sch = ((lane & 7) ^ sro) * 8;
    const ushort_t* gaBase = A + (size_t)(row0 + wave * 32 + sro) * CDIM + sch;
    const ushort_t* gwBase = W + (size_t)(col0 + wave * 32 + sro) * CDIM + sch;

    floatx4 acc[4][4];
    #pragma unroll
    for (int i = 0; i < 4; ++i)
        #pragma unroll
        for (int j = 0; j < 4; ++j)
            acc[i][j] = (floatx4){0.f, 0.f, 0.f, 0.f};

    const int q4 = lane >> 4, r16 = lane & 15;

    for (int kt = 0; kt < CDIM; kt += 64) {
        __syncthreads();
        #pragma unroll
        for (int i = 0; i < 4; ++i) {
            gload_lds16(gaBase + (size_t)i * 8 * CDIM + kt, &At[(wave * 32 + i * 8) * 64]);
            gload_lds16(gwBase + (size_t)i * 8 * CDIM + kt, &Wt[(wave * 32 + i * 8) * 64]);
        }
        __syncthreads();
        #pragma unroll
        for (int ks = 0; ks < 2; ++ks) {
            short8 af[4], bfr[4];
            #pragma unroll
            for (int mt = 0; mt < 4; ++mt) {
                const int row = wm * 64 + mt * 16 + r16;
                const int ch  = (ks * 4 + q4) ^ (row & 7);
                af[mt] = *(const short8*)&At[row * 64 + ch * 8];
            }
            #pragma unroll
            for (int nt = 0; nt < 4; ++nt) {
                const int row = wn * 64 + nt * 16 + r16;
                const int ch  = (ks * 4 + q4) ^ (row & 7);
                bfr[nt] = *(const short8*)&Wt[row * 64 + ch * 8];
            }
            #pragma unroll
            for (int mt = 0; mt < 4; ++mt)
                #pragma unroll
                for (int nt = 0; nt < 4; ++nt)
                    acc[mt][nt] = __builtin_amdgcn_mfma_f32_16x16x32_bf16(
                        af[mt], bfr[nt], acc[mt][nt], 0, 0, 0);
        }
    }

    // ---- epilogue: LDS-staged coalesced store + fused pool (z==0) ----
    __syncthreads();    // all LDS reads of the last K-tile complete
    const int b = row0 >> 12;
    const int m_base = row0 & 4095;
    #pragma unroll
    for (int nt = 0; nt < 4; ++nt) {
        const int coll = wn * 64 + nt * 16 + r16;     // col-local 0..127
        const float bb = bias[col0 + coll];
        float psum = 0.f;
        #pragma unroll
        for (int mt = 0; mt < 4; ++mt) {
            const int rowl = wm * 64 + mt * 16 + q4 * 4;
            #pragma unroll
            for (int r = 0; r < 4; ++r) {
                lds[(rowl + r) * 136 + coll] = f2bfu(acc[mt][nt][r] + bb);
                psum += acc[mt][nt][r];
            }
        }
        if (z == 0) {
            psum += __shfl_xor(psum, 16);
            psum += __shfl_xor(psum, 32);
            if (q4 == 0) {
                const int h = (col0 + coll) >> 6, d = (col0 + coll) & 63;
                atomicAdd(&agent[(size_t)(b * 12 + h) * 1024 + (m_base >> 8) * 64 + d],
                          psum * (1.0f / 256.0f));
            }
        }
    }
    __syncthreads();
    // 256 rows (128 m x 2 heads) x 128 B; 8 lanes per row, uint4 each.
    #pragma unroll
    for (int it = 0; it < 8; ++it) {
        const int task  = it * 256 + tid;
        const int chunk = task & 7;          // 16-B chunk within the row
        const int rh    = task >> 3;         // 0..255
        const int rowl  = rh >> 1, hl = rh & 1;
        const uint4 v = *(const uint4*)&lds[rowl * 136 + hl * 64 + chunk * 8];
        ushort_t* op = out + ((size_t)(b * 12 + (col0 >> 6) + hl) * 4096
                              + m_base + rowl) * 64 + chunk * 8;
        *(uint4*)op = v;
    }
}

// ---------- Kernel 4: stage 1 (agent -> keys/values), MFMA scores, z-split x16 --
// Part A (MFMA, verified round 9): S^T[a][tok] = mfma(A=ah(value+residual),
// B=K-rows); exp + pack2 -> 8-B E2 store per lane.
// Part B (vectorized, verified round 10): lane covers a d-pair; 2-way m split;
// shfl_xor(32) combine; float2 stores. Sp transposed [bh][a][z2].
__global__ __launch_bounds__(512) void stage1(
    const ushort_t* __restrict__ k_hm, const ushort_t* __restrict__ v_hm,
    const float* __restrict__ agent, float* __restrict__ Sp, float* __restrict__ avp)
{
    const int bh = blockIdx.x, z = blockIdx.y;   // z in [0,16)
    const int tid = threadIdx.x;
    const int lane = tid & 63;
    const int w = tid >> 6;              // wave 0..7
    const int g = lane >> 4;             // quad group 0..3
    const int t = lane & 15;
    __shared__ ushort_t E2[256 * 20];    // [m_local][a] bf16, rows padded to 40 B

    // ah A-fragments (value + residual), scale 0.125 — identical to stage2's
    short8 ahA[2], ahE[2];
    #pragma unroll
    for (int k0 = 0; k0 < 2; ++k0) {
        const float* p = agent + (size_t)bh * 1024 + t * 64 + k0 * 32 + g * 8;
        const float4 f0 = *(const float4*)p;
        const float4 f1 = *(const float4*)(p + 4);
        const float v[8] = {f0.x, f0.y, f0.z, f0.w, f1.x, f1.y, f1.z, f1.w};
        uint u[4], e[4];
        #pragma unroll
        for (int j = 0; j < 4; ++j) {
            const float a0 = v[2*j] * 0.125f, a1 = v[2*j+1] * 0.125f;
            u[j] = cvt2(a0, a1);
            float b0, b1; bf2(u[j], b0, b1);
            e[j] = cvt2(a0 - b0, a1 - b1);
        }
        ahA[k0] = mk8(u[0], u[1], u[2], u[3]);
        ahE[k0] = mk8(e[0], e[1], e[2], e[3]);
    }

    const int m0 = z * 256;
    const ushort_t* kb = k_hm + ((size_t)bh * 4096 + m0) * 64;

    #pragma unroll
    for (int ti = 0; ti < 2; ++ti) {
        const int row = w * 32 + ti * 16 + t;
        const ushort_t* kp = kb + (size_t)row * 64 + g * 8;
        const short8 kB0 = *(const short8*)(kp);
        const short8 kB1 = *(const short8*)(kp + 32);
        floatx4 sc = {0.f, 0.f, 0.f, 0.f};
        sc = __builtin_amdgcn_mfma_f32_16x16x32_bf16(ahA[0], kB0, sc, 0, 0, 0);
        sc = __builtin_amdgcn_mfma_f32_16x16x32_bf16(ahA[1], kB1, sc, 0, 0, 0);
        sc = __builtin_amdgcn_mfma_f32_16x16x32_bf16(ahE[0], kB0, sc, 0, 0, 0);
        sc = __builtin_amdgcn_mfma_f32_16x16x32_bf16(ahE[1], kB1, sc, 0, 0, 0);
        const uint P0 = pack2(__expf(sc[0]), __expf(sc[1]));
        const uint P1 = pack2(__expf(sc[2]), __expf(sc[3]));
        *(uint2*)&E2[(size_t)row * 20 + g * 4] = make_uint2(P0, P1);
    }
    __syncthreads();

    // part B: quad gg of agents, half of m (128 rows), mseg splits it 2x64;
    // lane ls covers d-pair (d0, d0+1).
    const int gg = (tid >> 6) & 3;
    const int half = tid >> 8;           // 0/1
    const int ls = lane & 31;
    const int mseg = lane >> 5;          // 0/1
    const int d0 = ls * 2;
    const int mb = half * 128 + mseg * 64;
    const ushort_t* vb = v_hm + ((size_t)bh * 4096 + m0 + mb) * 64 + d0;
    float ac[4][2];
    float ss[4];
    #pragma unroll
    for (int a = 0; a < 4; ++a) { ac[a][0] = 0.f; ac[a][1] = 0.f; ss[a] = 0.f; }
    for (int ml = 0; ml < 64; ++ml) {
        const uint vv = *(const uint*)(vb + (size_t)ml * 64);
        float v0, v1;
        bf2(vv, v0, v1);
        const uint2 ee = *(const uint2*)&E2[(size_t)(mb + ml) * 20 + gg * 4];
        float e0, e1, e2, e3;
        bf2(ee.x, e0, e1);
        bf2(ee.y, e2, e3);
        ac[0][0] += e0 * v0; ac[0][1] += e0 * v1; ss[0] += e0;
        ac[1][0] += e1 * v0; ac[1][1] += e1 * v1; ss[1] += e1;
        ac[2][0] += e2 * v0; ac[2][1] += e2 * v1; ss[2] += e2;
        ac[3][0] += e3 * v0; ac[3][1] += e3 * v1; ss[3] += e3;
    }
    #pragma unroll
    for (int a = 0; a < 4; ++a) {
        ac[a][0] += __shfl_xor(ac[a][0], 32);
        ac[a][1] += __shfl_xor(ac[a][1], 32);
        ss[a]    += __shfl_xor(ss[a], 32);
    }
    const int z2 = z * 2 + half;         // 0..31
    if (mseg == 0) {
        float* avz = avp + (size_t)(z2 * 96 + bh) * 1024;
        #pragma unroll
        for (int a = 0; a < 4; ++a)
            *(float2*)&avz[(gg * 4 + a) * 64 + d0] = make_float2(ac[a][0], ac[a][1]);
        if (ls == 0) {
            #pragma unroll
            for (int a = 0; a < 4; ++a)
                Sp[((size_t)bh * 16 + gg * 4 + a) * 32 + z2] = ss[a];
        }
    }
}

// ---------- Kernel 4b: reduce partials -> normalized agent_v (once per bh) ----
__global__ __launch_bounds__(256) void redu(
    const float* __restrict__ avp, const float* __restrict__ Sp,
    float* __restrict__ avn_g)
{
    const int bh = blockIdx.x;
    const int tid = threadIdx.x;
    const int i4 = tid * 4;
    const int a = i4 >> 6;
    floatx4 num = {0.f, 0.f, 0.f, 0.f};
    #pragma unroll
    for (int zz = 0; zz < 32; ++zz)
        num += *(const floatx4*)&avp[(size_t)(zz * 96 + bh) * 1024 + i4];
    const float* sp = Sp + ((size_t)bh * 16 + a) * 32;
    floatx4 dv = {0.f, 0.f, 0.f, 0.f};
    #pragma unroll
    for (int j = 0; j < 8; ++j)
        dv += *(const floatx4*)(sp + j * 4);
    const float r = 1.0f / (dv[0] + dv[1] + dv[2] + dv[3]);
    *(floatx4*)&avn_g[(size_t)bh * 1024 + i4] = num * r;
}

// ---------- Kernel 5: stage 2 (queries -> agents) via MFMA ----------
// Swapped-operand scheme (verified round 5). avn pre-reduced by redu.
__global__ __launch_bounds__(256) void stage2(
    const ushort_t* __restrict__ q_hm, const float* __restrict__ avn_g,
    const float* __restrict__ agent, const float* __restrict__ ab,
    float* __restrict__ out)
{
    const int nb = blockIdx.x;           // 16
    const int bh = blockIdx.y;           // 96
    const int b = bh / 12, h = bh % 12;
    const int tid = threadIdx.x;
    const int g = (tid >> 4) & 3;        // lane>>4 (quad group)
    const int t = tid & 15;              // lane&15
    const int w = tid >> 6;              // wave
    __shared__ float avn[1024];          // normalized agent_v, [a][d] fp32

    {
        const int i4 = tid * 4;
        *(floatx4*)&avn[i4] = *(const floatx4*)&avn_g[(size_t)bh * 1024 + i4];
    }
    __syncthreads();

    // ah A-fragments (value + residual): lane holds ah[t][k0*32 + g*8 + j]*scale
    short8 ahA[2], ahE[2];
    #pragma unroll
    for (int k0 = 0; k0 < 2; ++k0) {
        const float* p = agent + (size_t)bh * 1024 + t * 64 + k0 * 32 + g * 8;
        const float4 f0 = *(const float4*)p;
        const float4 f1 = *(const float4*)(p + 4);
        const float v[8] = {f0.x, f0.y, f0.z, f0.w, f1.x, f1.y, f1.z, f1.w};
        uint u[4], e[4];
        #pragma unroll
        for (int j = 0; j < 4; ++j) {
            const float a0 = v[2*j] * 0.125f, a1 = v[2*j+1] * 0.125f;
            u[j] = cvt2(a0, a1);
            float b0, b1; bf2(u[j], b0, b1);
            e[j] = cvt2(a0 - b0, a1 - b1);
        }
        ahA[k0] = mk8(u[0], u[1], u[2], u[3]);
        ahE[k0] = mk8(e[0], e[1], e[2], e[3]);
    }

    // av^T A-fragments (value + residual): lane holds avn[8g+j][dt*16 + t]; g>=2 zero
    short8 avf[4], ave[4];
    #pragma unroll
    for (int dt = 0; dt < 4; ++dt) {
        uint u[4] = {0, 0, 0, 0}, e[4] = {0, 0, 0, 0};
        if (g < 2) {
            #pragma unroll
            for (int j = 0; j < 4; ++j) {
                const float a0 = avn[(8*g + 2*j)     * 64 + dt * 16 + t];
                const float a1 = avn[(8*g + 2*j + 1) * 64 + dt * 16 + t];
                u[j] = cvt2(a0, a1);
                float b0, b1; bf2(u[j], b0, b1);
                e[j] = cvt2(a0 - b0, a1 - b1);
            }
        }
        avf[dt] = mk8(u[0], u[1], u[2], u[3]);
        ave[dt] = mk8(e[0], e[1], e[2], e[3]);
    }

    float abv[4];
    #pragma unroll
    for (int r = 0; r < 4; ++r) abv[r] = ab[h * 16 + 4 * g + r];

    const int src0 = (t + 32 * g) & 63;
    const int src1 = (src0 + 16) & 63;
    const int n0 = nb * 256 + w * 64;
    const ushort_t* qb = q_hm + ((size_t)bh * 4096 + n0) * 64;
    float* ob = out + ((size_t)b * 4096 + n0) * CDIM + h * 64;

    #pragma unroll
    for (int ti = 0; ti < 4; ++ti) {
        // Q B-fragments: lane holds Q[ti*16+t][k0*32 + g*8 + j]
        const ushort_t* qp = qb + (size_t)(ti * 16 + t) * 64 + g * 8;
        const short8 qB0 = *(const short8*)(qp);
        const short8 qB1 = *(const short8*)(qp + 32);

        floatx4 sc = {0.f, 0.f, 0.f, 0.f};
        sc = __builtin_amdgcn_mfma_f32_16x16x32_bf16(ahA[0], qB0, sc, 0, 0, 0);
        sc = __builtin_amdgcn_mfma_f32_16x16x32_bf16(ahA[1], qB1, sc, 0, 0, 0);
        sc = __builtin_amdgcn_mfma_f32_16x16x32_bf16(ahE[0], qB0, sc, 0, 0, 0);
        sc = __builtin_amdgcn_mfma_f32_16x16x32_bf16(ahE[1], qB1, sc, 0, 0, 0);

        // softmax over agents (rows): in-lane + cross-group
        const float e0 = __expf(sc[0] + abv[0]);
        const float e1 = __expf(sc[1] + abv[1]);
        const float e2 = __expf(sc[2] + abv[2]);
        const float e3 = __expf(sc[3] + abv[3]);
        float s = e0 + e1 + e2 + e3;
        s += __shfl_xor(s, 16);
        s += __shfl_xor(s, 32);
        const float rs = 1.0f / s;
        const float p0 = e0 * rs, p1 = e1 * rs, p2 = e2 * rs, p3 = e3 * rs;

        // pack own P (agents 4g..4g+3, token t) + residual
        const uint P0 = cvt2(p0, p1), P1 = cvt2(p2, p3);
        float q0, q1, q2, q3;
        bf2(P0, q0, q1); bf2(P1, q2, q3);
        const uint E0 = cvt2(p0 - q0, p1 - q1), E1 = cvt2(p2 - q2, p3 - q3);

        // regroup into K=32-padded B-fragment: k=8g+j -> agents from groups 2g, 2g+1
        uint w0 = __shfl(P0, src0), w1 = __shfl(P1, src0);
        uint w2 = __shfl(P0, src1), w3 = __shfl(P1, src1);
        uint x0 = __shfl(E0, src0), x1 = __shfl(E1, src0);
        uint x2 = __shfl(E0, src1), x3 = __shfl(E1, src1);
        if (g >= 2) { w0 = w1 = w2 = w3 = 0; x0 = x1 = x2 = x3 = 0; }
        const short8 pf = mk8(w0, w1, w2, w3);
        const short8 pe = mk8(x0, x1, x2, x3);

        // PV: out^T[dt*16 + 4g + r][t], residual-corrected
        float* op = ob + (size_t)(ti * 16 + t) * CDIM + 4 * g;
        #pragma unroll
        for (int dt = 0; dt < 4; ++dt) {
            floatx4 od = {0.f, 0.f, 0.f, 0.f};
            od = __builtin_amdgcn_mfma_f32_16x16x32_bf16(avf[dt], pf, od, 0, 0, 0);
            od = __builtin_amdgcn_mfma_f32_16x16x32_bf16(avf[dt], pe, od, 0, 0, 0);
            od = __builtin_amdgcn_mfma_f32_16x16x32_bf16(ave[dt], pf, od, 0, 0, 0);
            *(floatx4*)(op + dt * 16) = od;
        }
    }
}

// ---------- launcher ----------
extern "C" void kernel_launch(void* const* d_in, const int* in_sizes, int n_in,
                              void* d_out, int out_size, void* d_ws, size_t ws_size,
                              hipStream_t stream) {
    (void)in_sizes; (void)n_in; (void)out_size; (void)ws_size;
    const float* s1 = (const float*)d_in[0];
    const float* s2 = (const float*)d_in[1];
    const float* Wq = (const float*)d_in[2];
    const float* bq = (const float*)d_in[3];
    const float* Wk = (const float*)d_in[4];
    const float* bk = (const float*)d_in[5];
    const float* Wv = (const float*)d_in[6];
    const float* bv = (const float*)d_in[7];
    const float* na = (const float*)d_in[9];
    const float* ha = (const float*)d_in[12];
    const float* wa = (const float*)d_in[13];
    float* out = (float*)d_out;

    char* ws = (char*)d_ws;
    ushort_t* q_hm = (ushort_t*)(ws);                 // 50,331,648 B  [96][4096][64]
    ushort_t* k_hm = (ushort_t*)(ws + 50331648);      // 50,331,648 B
    ushort_t* v_hm = (ushort_t*)(ws + 100663296);     // 50,331,648 B
    float* agent   = (float*)(ws + 150994944);        //    393,216 B  [96][16][64]
    float* Sp      = (float*)(ws + 151388160);        //    196,608 B  [96][16][32]  (transposed)
    float* ab      = (float*)(ws + 151584768);        //        768 B
    float* avn_g   = (float*)(ws + 151585536);        //    393,216 B  [96][16][64]
    ushort_t* wb   = (ushort_t*)(ws + 151978752);     //  3,538,944 B  [3][768][768]
    ushort_t* abuf = (ushort_t*)(ws + 155517696);     // 100,663,296 B [2][32768][768]  (live cvt..gemm)
    float* avp     = (float*)(ws + 155517696);        // 12,582,912 B  [32][96][16][64] (live stage1..redu, overlays dead abuf)

    cvt_all  <<<dim3(25537),     256, 0, stream>>>(s1, s2, Wq, Wk, Wv, bq,
                                                   na, ha, wa, abuf, wb, agent, ab);
    gemm_qkv <<<dim3(256, 6, 3), 256, 0, stream>>>(abuf, wb, bq, bk, bv,
                                                   q_hm, k_hm, v_hm, agent);
    stage1   <<<dim3(96, 16),    512, 0, stream>>>(k_hm, v_hm, agent, Sp, avp);
    redu     <<<dim3(96),        256, 0, stream>>>(avp, Sp, avn_g);
    stage2   <<<dim3(16, 96),    256, 0, stream>>>(q_hm, avn_g, agent, ab, out);
}